// Round 13
// baseline (398.035 us; speedup 1.0000x reference)
//
#include <hip/hip_runtime.h>
#include <hip/hip_fp16.h>

typedef _Float16 half8 __attribute__((ext_vector_type(8)));
typedef float f32x4 __attribute__((ext_vector_type(4)));

constexpr int Bn = 4, Tn = 2048, Dn = 1024, Hn = 8, Kn = 128, Vn = 128;
constexpr int Sn = 512, Cn = 256, Rn = 8, Wn = 512;
constexpr float NEGV = 1.0e30f;
constexpr float INV_TAU = 0.08838834764831845f;  // 1/sqrt(128)

__device__ __forceinline__ half8 ldh8(const __half* p) {
  return *reinterpret_cast<const half8*>(p);
}
__device__ __forceinline__ void sth8(__half* p, half8 v) {
  *reinterpret_cast<half8*>(p) = v;
}
__device__ __forceinline__ f32x4 mfma16(half8 a, half8 b, f32x4 c) {
  return __builtin_amdgcn_mfma_f32_16x16x32_f16(a, b, c, 0, 0, 0);
}

// ---------------- RMSNorm -> split f16 (hi + residual) ----------------
__global__ __launch_bounds__(256) void rms3_k(const float* __restrict__ x,
                                              const float* __restrict__ g,
                                              __half* __restrict__ xth,
                                              __half* __restrict__ xtl) {
  const int row = blockIdx.x;
  const int tid = threadIdx.x;
  const float4 v = reinterpret_cast<const float4*>(x + (size_t)row * Dn)[tid];
  float ss = v.x * v.x + v.y * v.y + v.z * v.z + v.w * v.w;
#pragma unroll
  for (int o = 32; o > 0; o >>= 1) ss += __shfl_xor(ss, o);
  __shared__ float red[4];
  if ((tid & 63) == 0) red[tid >> 6] = ss;
  __syncthreads();
  const float tot = red[0] + red[1] + red[2] + red[3];
  const float sc = rsqrtf(tot * (1.0f / Dn) + 1e-6f);
  const float4 gv = reinterpret_cast<const float4*>(g)[tid];
  float vv[4] = {v.x * sc * gv.x, v.y * sc * gv.y, v.z * sc * gv.z,
                 v.w * sc * gv.w};
  __half hi[4], lo[4];
#pragma unroll
  for (int e = 0; e < 4; ++e) {
    hi[e] = __float2half(vv[e]);
    lo[e] = __float2half(vv[e] - __half2float(hi[e]));
  }
  __half2* oph = reinterpret_cast<__half2*>(xth + (size_t)row * Dn + tid * 4);
  __half2* opl = reinterpret_cast<__half2*>(xtl + (size_t)row * Dn + tid * 4);
  oph[0] = __halves2half2(hi[0], hi[1]);
  oph[1] = __halves2half2(hi[2], hi[3]);
  opl[0] = __halves2half2(lo[0], lo[1]);
  opl[1] = __halves2half2(lo[2], lo[3]);
}

// -------- fused transpose+convert of all 4 weights (z selects) --------
__global__ __launch_bounds__(256) void transall_k(
    const float* __restrict__ Wq, const float* __restrict__ Wv,
    const float* __restrict__ Wo, const float* __restrict__ Wk,
    __half* __restrict__ wqt, __half* __restrict__ wvt,
    __half* __restrict__ wot, __half* __restrict__ wkth,
    __half* __restrict__ wktl) {
  __shared__ float ts[32][33];
  const int z = blockIdx.z;
  const float* src = (z == 0) ? Wq : (z == 1) ? Wv : (z == 2) ? Wo : Wk;
  const int bx = blockIdx.x, by = blockIdx.y;
  const int j = threadIdx.x & 31, i0 = threadIdx.x >> 5;
#pragma unroll
  for (int rr = 0; rr < 4; ++rr) {
    const int row = i0 + rr * 8;
    ts[row][j] = src[(size_t)(by * 32 + row) * 1024 + bx * 32 + j];
  }
  __syncthreads();
  if (z < 3) {
    __half* dst = (z == 0) ? wqt : (z == 1) ? wvt : wot;
#pragma unroll
    for (int rr = 0; rr < 4; ++rr) {
      const int row = i0 + rr * 8;
      dst[(size_t)(bx * 32 + row) * 1024 + by * 32 + j] =
          __float2half(ts[j][row]);
    }
  } else {
#pragma unroll
    for (int rr = 0; rr < 4; ++rr) {
      const int row = i0 + rr * 8;
      const float v = ts[j][row];
      const __half hi = __float2half(v);
      wkth[(size_t)(bx * 32 + row) * 1024 + by * 32 + j] = hi;
      wktl[(size_t)(bx * 32 + row) * 1024 + by * 32 + j] =
          __float2half(v - __half2float(hi));
    }
  }
}

// ---------------- codebook squared norms ----------------
__global__ __launch_bounds__(256) void cb2_k(const float* __restrict__ cb,
                                             float* __restrict__ cb2v) {
  const int idx = blockIdx.x * 256 + threadIdx.x;  // < H*S
  const float4* rp = reinterpret_cast<const float4*>(cb + (size_t)idx * Kn);
  float ss = 0.f;
#pragma unroll 8
  for (int i = 0; i < Kn / 4; ++i) {
    const float4 v = rp[i];
    ss += v.x * v.x + v.y * v.y + v.z * v.z + v.w * v.w;
  }
  cb2v[idx] = ss;
}

// -------- f32 -> f16 conversion: cb (hi+lo) and xl_r (hi only) --------
__global__ __launch_bounds__(256) void cvt2_k(const float* __restrict__ cb,
                                              const float* __restrict__ xlr,
                                              __half* __restrict__ cbh,
                                              __half* __restrict__ cbl,
                                              __half* __restrict__ xlrh) {
  const int i = blockIdx.x * 256 + threadIdx.x;
  constexpr int NE = Hn * Sn * Kn;  // 524288
  if (i < NE) {
    const float v = cb[i];
    const __half hi = __float2half(v);
    cbh[i] = hi;
    cbl[i] = __float2half(v - __half2float(hi));
  } else {
    xlrh[i - NE] = __float2half(xlr[i - NE]);
  }
}

// ---------------- duv[h][j] = (xl_v - xl_u) . xl_r[h][j] ----------------
__global__ __launch_bounds__(256) void duv_k(const float* __restrict__ xlr,
                                             const float* __restrict__ xlu,
                                             const float* __restrict__ xlv,
                                             float* __restrict__ duv) {
  const int h = blockIdx.x;
  const float* up = xlu + h * Kn;
  const float* vp = xlv + h * Kn;
  for (int j = threadIdx.x; j < Wn; j += 256) {
    const float* rp = xlr + ((size_t)h * Wn + j) * Kn;
    float s = 0.f;
#pragma unroll 8
    for (int d = 0; d < Kn; ++d) s = fmaf(vp[d] - up[d], rp[d], s);
    duv[h * Wn + j] = s;
  }
}

// ------- split-f16 MFMA k-projection: k = (xh+xl).(wh+wl), 3 terms ---------
__global__ __launch_bounds__(256, 2) void kproj_k(
    const __half* __restrict__ Ah, const __half* __restrict__ Al,
    const __half* __restrict__ Bh, const __half* __restrict__ Bl,
    __half* __restrict__ Ch, __half* __restrict__ Cl, int M, int KD) {
  __shared__ __half AsH[128 * 72];
  __shared__ __half AsL[128 * 72];
  __shared__ __half BsH[128 * 72];
  __shared__ __half BsL[128 * 72];
  const int tid = threadIdx.x;
  const int lane = tid & 63, wq = tid >> 6;
  const int lrow = lane & 15, lk8 = (lane >> 4) << 3;
  const int m0 = blockIdx.x * 128, n0 = blockIdx.y * 128;
  const int srow = tid >> 2, spart = tid & 3;

  f32x4 acc[2][8];
#pragma unroll
  for (int mt = 0; mt < 2; ++mt)
#pragma unroll
    for (int nt = 0; nt < 8; ++nt) acc[mt][nt] = (f32x4){0.f, 0.f, 0.f, 0.f};

  for (int kt = 0; kt < KD; kt += 64) {
    __syncthreads();
#pragma unroll
    for (int hh = 0; hh < 2; ++hh) {
      const int row = srow + hh * 64;
      const size_t ao = (size_t)(m0 + row) * KD + kt + spart * 16;
      const size_t bo = (size_t)(n0 + row) * KD + kt + spart * 16;
      sth8(&AsH[row * 72 + spart * 16], ldh8(Ah + ao));
      sth8(&AsH[row * 72 + spart * 16 + 8], ldh8(Ah + ao + 8));
      sth8(&AsL[row * 72 + spart * 16], ldh8(Al + ao));
      sth8(&AsL[row * 72 + spart * 16 + 8], ldh8(Al + ao + 8));
      sth8(&BsH[row * 72 + spart * 16], ldh8(Bh + bo));
      sth8(&BsH[row * 72 + spart * 16 + 8], ldh8(Bh + bo + 8));
      sth8(&BsL[row * 72 + spart * 16], ldh8(Bl + bo));
      sth8(&BsL[row * 72 + spart * 16 + 8], ldh8(Bl + bo + 8));
    }
    __syncthreads();
#pragma unroll
    for (int ks = 0; ks < 2; ++ks) {
      const half8 a0h = ldh8(&AsH[(32 * wq + lrow) * 72 + lk8 + 32 * ks]);
      const half8 a1h = ldh8(&AsH[(32 * wq + 16 + lrow) * 72 + lk8 + 32 * ks]);
      const half8 a0l = ldh8(&AsL[(32 * wq + lrow) * 72 + lk8 + 32 * ks]);
      const half8 a1l = ldh8(&AsL[(32 * wq + 16 + lrow) * 72 + lk8 + 32 * ks]);
#pragma unroll
      for (int nt = 0; nt < 8; ++nt) {
        const half8 bh = ldh8(&BsH[(16 * nt + lrow) * 72 + lk8 + 32 * ks]);
        const half8 bl = ldh8(&BsL[(16 * nt + lrow) * 72 + lk8 + 32 * ks]);
        acc[0][nt] = mfma16(a0h, bh, acc[0][nt]);
        acc[0][nt] = mfma16(a0h, bl, acc[0][nt]);
        acc[0][nt] = mfma16(a0l, bh, acc[0][nt]);
        acc[1][nt] = mfma16(a1h, bh, acc[1][nt]);
        acc[1][nt] = mfma16(a1h, bl, acc[1][nt]);
        acc[1][nt] = mfma16(a1l, bh, acc[1][nt]);
      }
    }
  }
  __half* OH = Ch + (size_t)(n0 >> 7) * M * 128;
  __half* OL = Cl + (size_t)(n0 >> 7) * M * 128;
#pragma unroll
  for (int mt = 0; mt < 2; ++mt)
#pragma unroll
    for (int nt = 0; nt < 8; ++nt)
#pragma unroll
      for (int reg = 0; reg < 4; ++reg) {
        const int row = m0 + 32 * wq + 16 * mt + 4 * (lane >> 4) + reg;
        const float v = acc[mt][nt][reg];
        const __half hi = __float2half(v);
        OH[(size_t)row * 128 + 16 * nt + lrow] = hi;
        OL[(size_t)row * 128 + 16 * nt + lrow] =
            __float2half(v - __half2float(hi));
      }
}

// ------------- f16 MFMA NT GEMM: C[m][n] = sum_k A[m][k] * Bt[n][k] --------
template <int MODE>
__global__ __launch_bounds__(256, 4) void gemmh_k(const __half* __restrict__ A,
                                                  const __half* __restrict__ Bt,
                                                  void* __restrict__ Cout,
                                                  int M, int N, int KD) {
  __shared__ __half As[128 * 72];
  __shared__ __half Bs[128 * 72];
  const int tid = threadIdx.x;
  const int lane = tid & 63, wq = tid >> 6;
  const int lrow = lane & 15, lk8 = (lane >> 4) << 3;
  const int m0 = blockIdx.x * 128, n0 = blockIdx.y * 128;
  const int srow = tid >> 2, spart = tid & 3;

  f32x4 acc[2][8];
#pragma unroll
  for (int mt = 0; mt < 2; ++mt)
#pragma unroll
    for (int nt = 0; nt < 8; ++nt) acc[mt][nt] = (f32x4){0.f, 0.f, 0.f, 0.f};

  for (int kt = 0; kt < KD; kt += 64) {
    __syncthreads();
#pragma unroll
    for (int hh = 0; hh < 2; ++hh) {
      const int row = srow + hh * 64;
      const __half* pa = A + (size_t)(m0 + row) * KD + kt + spart * 16;
      const __half* pb = Bt + (size_t)(n0 + row) * KD + kt + spart * 16;
      sth8(&As[row * 72 + spart * 16], ldh8(pa));
      sth8(&As[row * 72 + spart * 16 + 8], ldh8(pa + 8));
      sth8(&Bs[row * 72 + spart * 16], ldh8(pb));
      sth8(&Bs[row * 72 + spart * 16 + 8], ldh8(pb + 8));
    }
    __syncthreads();
#pragma unroll
    for (int ks = 0; ks < 2; ++ks) {
      half8 a0 = ldh8(&As[(32 * wq + lrow) * 72 + lk8 + 32 * ks]);
      half8 a1 = ldh8(&As[(32 * wq + 16 + lrow) * 72 + lk8 + 32 * ks]);
#pragma unroll
      for (int nt = 0; nt < 8; ++nt) {
        half8 b = ldh8(&Bs[(16 * nt + lrow) * 72 + lk8 + 32 * ks]);
        acc[0][nt] = mfma16(a0, b, acc[0][nt]);
        acc[1][nt] = mfma16(a1, b, acc[1][nt]);
      }
    }
  }
  if (MODE == 0) {
    __half* O = reinterpret_cast<__half*>(Cout) + (size_t)(n0 >> 7) * M * 128;
#pragma unroll
    for (int mt = 0; mt < 2; ++mt)
#pragma unroll
      for (int nt = 0; nt < 8; ++nt)
#pragma unroll
        for (int reg = 0; reg < 4; ++reg) {
          const int row = m0 + 32 * wq + 16 * mt + 4 * (lane >> 4) + reg;
          O[(size_t)row * 128 + 16 * nt + lrow] = __float2half(acc[mt][nt][reg]);
        }
  } else {
    float* O = reinterpret_cast<float*>(Cout);
#pragma unroll
    for (int mt = 0; mt < 2; ++mt)
#pragma unroll
      for (int nt = 0; nt < 8; ++nt)
#pragma unroll
        for (int reg = 0; reg < 4; ++reg) {
          const int row = m0 + 32 * wq + 16 * mt + 4 * (lane >> 4) + reg;
          O[(size_t)row * N + n0 + 16 * nt + lrow] = acc[mt][nt][reg];
        }
  }
}

// ---------- split-f16 MFMA dot + argmin: z = argmin_s ||k - c_s||^2 --------
__global__ __launch_bounds__(256, 2) void argmin3_k(
    const __half* __restrict__ kbh, const __half* __restrict__ kbl,
    const __half* __restrict__ cbh, const __half* __restrict__ cbl,
    const float* __restrict__ cb2v, int* __restrict__ zb) {
  __shared__ __half BsH[64 * 136];
  __shared__ __half BsL[64 * 136];
  const int tid = threadIdx.x;
  const int lane = tid & 63, wq = tid >> 6;
  const int lrow = lane & 15, lk8 = (lane >> 4) << 3;
  const int m0 = blockIdx.x * 128;
  const int h = blockIdx.y;
  const int srow = tid >> 2, spart = tid & 3;
  const size_t kbase = (size_t)h * (Bn * Tn);

  half8 ah[2][4], al[2][4];
#pragma unroll
  for (int mt = 0; mt < 2; ++mt)
#pragma unroll
    for (int ks = 0; ks < 4; ++ks) {
      const size_t off =
          (kbase + m0 + 32 * wq + 16 * mt + lrow) * 128 + lk8 + 32 * ks;
      ah[mt][ks] = ldh8(kbh + off);
      al[mt][ks] = ldh8(kbl + off);
    }

  float best[2][4];
  int bidx[2][4];
#pragma unroll
  for (int mt = 0; mt < 2; ++mt)
#pragma unroll
    for (int reg = 0; reg < 4; ++reg) {
      best[mt][reg] = 3.0e38f;
      bidx[mt][reg] = 0;
    }

  for (int s0 = 0; s0 < Sn; s0 += 64) {
    __syncthreads();
    {
      const size_t bo = ((size_t)h * Sn + s0 + srow) * 128 + spart * 32;
      sth8(&BsH[srow * 136 + spart * 32], ldh8(cbh + bo));
      sth8(&BsH[srow * 136 + spart * 32 + 8], ldh8(cbh + bo + 8));
      sth8(&BsH[srow * 136 + spart * 32 + 16], ldh8(cbh + bo + 16));
      sth8(&BsH[srow * 136 + spart * 32 + 24], ldh8(cbh + bo + 24));
      sth8(&BsL[srow * 136 + spart * 32], ldh8(cbl + bo));
      sth8(&BsL[srow * 136 + spart * 32 + 8], ldh8(cbl + bo + 8));
      sth8(&BsL[srow * 136 + spart * 32 + 16], ldh8(cbl + bo + 16));
      sth8(&BsL[srow * 136 + spart * 32 + 24], ldh8(cbl + bo + 24));
    }
    __syncthreads();
    f32x4 acc[2][4];
#pragma unroll
    for (int mt = 0; mt < 2; ++mt)
#pragma unroll
      for (int nt = 0; nt < 4; ++nt) acc[mt][nt] = (f32x4){0.f, 0.f, 0.f, 0.f};
#pragma unroll
    for (int ks = 0; ks < 4; ++ks)
#pragma unroll
      for (int nt = 0; nt < 4; ++nt) {
        const half8 bh = ldh8(&BsH[(16 * nt + lrow) * 136 + lk8 + 32 * ks]);
        const half8 bl = ldh8(&BsL[(16 * nt + lrow) * 136 + lk8 + 32 * ks]);
        acc[0][nt] = mfma16(ah[0][ks], bh, acc[0][nt]);
        acc[0][nt] = mfma16(ah[0][ks], bl, acc[0][nt]);
        acc[0][nt] = mfma16(al[0][ks], bh, acc[0][nt]);
        acc[1][nt] = mfma16(ah[1][ks], bh, acc[1][nt]);
        acc[1][nt] = mfma16(ah[1][ks], bl, acc[1][nt]);
        acc[1][nt] = mfma16(al[1][ks], bh, acc[1][nt]);
      }
#pragma unroll
    for (int mt = 0; mt < 2; ++mt)
#pragma unroll
      for (int nt = 0; nt < 4; ++nt) {
        const int s = s0 + 16 * nt + lrow;
        const float c2 = cb2v[h * Sn + s];
#pragma unroll
        for (int reg = 0; reg < 4; ++reg) {
          const float d2 = c2 - 2.0f * acc[mt][nt][reg];
          if (d2 < best[mt][reg]) {
            best[mt][reg] = d2;
            bidx[mt][reg] = s;
          }
        }
      }
  }
#pragma unroll
  for (int xb = 1; xb <= 8; xb <<= 1) {
#pragma unroll
    for (int mt = 0; mt < 2; ++mt)
#pragma unroll
      for (int reg = 0; reg < 4; ++reg) {
        const float ob = __shfl_xor(best[mt][reg], xb);
        const int oi = __shfl_xor(bidx[mt][reg], xb);
        if (ob < best[mt][reg] ||
            (ob == best[mt][reg] && oi < bidx[mt][reg])) {
          best[mt][reg] = ob;
          bidx[mt][reg] = oi;
        }
      }
  }
  if (lrow == 0) {
#pragma unroll
    for (int mt = 0; mt < 2; ++mt)
#pragma unroll
      for (int reg = 0; reg < 4; ++reg) {
        const int row = m0 + 32 * wq + 16 * mt + 4 * (lane >> 4) + reg;
        zb[kbase + row] = bidx[mt][reg];
      }
  }
}

// ------- scan2: cumulative cluster stats, 256 blocks x 1024 thr ------------
__global__ __launch_bounds__(1024) void scan2_k(const int* __restrict__ zb,
                                                const __half* __restrict__ vb,
                                                __half* __restrict__ udl,
                                                float* __restrict__ biasv) {
  __shared__ float acc[64][128];
  __shared__ float cnt[64];
  const int tid = threadIdx.x;
  const int sc = blockIdx.x, b = blockIdx.y, h = blockIdx.z;
  const int s0 = sc * 64;
  for (int i = tid; i < 64 * 128; i += 1024) acc[i >> 7][i & 127] = 0.f;
  if (tid < 64) cnt[tid] = 0.f;
  __syncthreads();
  const size_t tokH = (size_t)h * (Bn * Tn) + (size_t)b * Tn;
  const int dd = tid & 127, slice = tid >> 7;  // 8 slices
  for (int r = 0; r < Rn; ++r) {
    for (int i = tid; i < 64 * 128; i += 1024) {
      const int srow = i >> 7, d = i & 127;
      const float c = cnt[srow];
      udl[((((size_t)h * Bn + b) * Rn + r) * Sn + s0 + srow) * Vn + d] =
          __float2half(acc[srow][d] / fmaxf(c, 1.f));
    }
    if (tid < 64) {
      const float c = cnt[tid];
      biasv[(((size_t)h * Bn + b) * Rn + r) * Sn + s0 + tid] =
          (c > 0.f) ? logf(c) : -NEGV;
    }
    __syncthreads();
    if (r >= 1 && r < 7) {
      const int tb = (r - 1) * Cn;
#pragma unroll 4
      for (int u = 0; u < 32; ++u) {
        const int tok = tb + u * 8 + slice;
        const int s = zb[tokH + tok];
        if (s >= s0 && s < s0 + 64) {
          const float v = __half2float(vb[(tokH + tok) * Vn + dd]);
          atomicAdd(&acc[s - s0][dd], v);
          if (dd == 0) atomicAdd(&cnt[s - s0], 1.0f);
        }
      }
    }
    __syncthreads();
  }
}

// --- MFMA fused attention v10: attn9 + vectorized Vt + early global loads --
// 1 block per (b,r,h), 512 thr = 8 waves; wave owns 32 rows (2 m-tiles).
__global__ __launch_bounds__(512, 2) void attn10_k(
    const __half* __restrict__ qbh, const __half* __restrict__ vbh,
    const __half* __restrict__ udl, const __half* __restrict__ cbh,
    const __half* __restrict__ xlrh, const float* __restrict__ biasv,
    const float* __restrict__ duv, const int* __restrict__ zb,
    const float* __restrict__ xlu, __half* __restrict__ aout) {
  __shared__ __half XS[320 * 136];   // circular xlr window (mod 320)
  __shared__ __half KS[64 * 136];    // K chunk
  __shared__ __half VtS[128 * 72];   // V^T chunk (XOR-swizzled granules)
  __shared__ __half SC[8 * 2304];    // per-wave scratch: E [16][82] / P [32][72]

  const int tid = threadIdx.x;
  const int lane = tid & 63, wq = tid >> 6;
  const int lrow = lane & 15, hi = lane >> 4, lk8 = hi << 3;
  const int bx = blockIdx.x;
  const int b = bx >> 3, r = bx & 7;
  const int h = blockIdx.y;
  const int cm0 = 32 * wq;
  const size_t tokH = (size_t)h * (Bn * Tn) + (size_t)b * Tn;
  const size_t sBase = (((size_t)h * Bn + b) * Rn + r) * Sn;
  const int tBlk = r * Cn;
  __half* Sw = &SC[wq * 2304];

  // A-frags: qu = q + xl_u (rows cm0+16mt+lrow)
  half8 a[2][4];
#pragma unroll
  for (int mt = 0; mt < 2; ++mt) {
    const size_t qrow = (tokH + tBlk + cm0 + 16 * mt + lrow) * Kn;
#pragma unroll
    for (int ks = 0; ks < 4; ++ks) {
      const int col = lk8 + 32 * ks;
      half8 q = ldh8(qbh + qrow + col);
      const float* up = xlu + h * Kn + col;
      half8 t;
#pragma unroll
      for (int e = 0; e < 8; ++e) t[e] = (_Float16)((float)q[e] + up[e]);
      a[mt][ks] = t;
    }
  }

  float mR[2][4], lR[2][4];
  f32x4 Oacc[2][8];
#pragma unroll
  for (int mt = 0; mt < 2; ++mt) {
#pragma unroll
    for (int i = 0; i < 4; ++i) {
      mR[mt][i] = -NEGV;
      lR[mt][i] = 0.f;
    }
#pragma unroll
    for (int nt = 0; nt < 8; ++nt) Oacc[mt][nt] = (f32x4){0.f, 0.f, 0.f, 0.f};
  }

  const int krow = tid >> 3, kpart = tid & 7;  // K staging (64 rows x 8 thr)
  // Vt staging: thread owns token-row = lane, dim-group colg = wq
  const int vgbase = (((lane >> 3) ^ (wq & 7)) << 3) + (lane & 7);

  // r==0: cache + recent-prev masked -> chunks 12..15; r==1: cache masked
  const int chStart = (r >= 2) ? 0 : ((r == 1) ? 8 : 12);
  const int chFirstRecent = (chStart > 8) ? chStart : 8;

  for (int ch = chStart; ch < 16; ++ch) {
    const bool isC = (ch < 8);
    const int s0 = ch * 64;
    const int w0 = (ch - 8) * 64;
    const int w0m = (w0 >= 320) ? w0 - 320 : w0;  // w0 mod 320

    // ---- early global loads (overlap with prior chunk's compute) ----
    half8 gK0, gK1, gV0, gV1, gX0, gX1;
    bool haveX = false;
    if (isC) {
      const __half* ks = cbh + ((size_t)h * Sn + s0 + krow) * Kn + kpart * 16;
      gK0 = ldh8(ks);
      gK1 = ldh8(ks + 8);
      const __half* us = udl + (sBase + s0 + lane) * Vn + wq * 16;
      gV0 = ldh8(us);
      gV1 = ldh8(us + 8);
    } else {
      int tk = (r - 1) * Cn + w0 + krow;
      if (tk < 0) tk = 0;
      const int code = zb[tokH + tk];
      const __half* ks = cbh + ((size_t)h * Sn + code) * Kn + kpart * 16;
      gK0 = ldh8(ks);
      gK1 = ldh8(ks + 8);
      int tv = (r - 1) * Cn + w0 + lane;
      if (tv < 0) tv = 0;
      const __half* vs = vbh + (tokH + tv) * Kn + wq * 16;
      gV0 = ldh8(vs);
      gV1 = ldh8(vs + 8);
      if (ch != chFirstRecent) {
        const int jl = 256 + (tid >> 3);
        int j = w0 + jl;
        j = j > Wn - 1 ? Wn - 1 : j;
        const __half* xs = xlrh + ((size_t)h * Wn + j) * Kn + (tid & 7) * 16;
        gX0 = ldh8(xs);
        gX1 = ldh8(xs + 8);
        haveX = true;
      }
    }

    __syncthreads();  // (1) prior chunk LDS reads complete

    // ---- LDS writes from registers ----
    sth8(&KS[krow * 136 + kpart * 16], gK0);
    sth8(&KS[krow * 136 + kpart * 16 + 8], gK1);
#pragma unroll
    for (int e = 0; e < 8; ++e)
      VtS[(wq * 16 + e) * 72 + vgbase] = ((const __half*)&gV0)[e];
#pragma unroll
    for (int e = 0; e < 8; ++e)
      VtS[(wq * 16 + 8 + e) * 72 + vgbase] = ((const __half*)&gV1)[e];
    if (!isC) {
      if (ch == chFirstRecent) {
        for (int jl = tid >> 1; jl < 320; jl += 256) {
          const int p2 = tid & 1;
          int j = w0 + jl;
          j = j > Wn - 1 ? Wn - 1 : j;
          int pos = w0m + jl;
          if (pos >= 320) pos -= 320;
          const __half* xs = xlrh + ((size_t)h * Wn + j) * Kn + 64 * p2;
          __half* xd = &XS[pos * 136 + 64 * p2];
#pragma unroll
          for (int g8 = 0; g8 < 8; ++g8) sth8(xd + 8 * g8, ldh8(xs + 8 * g8));
        }
      } else if (haveX) {
        const int jl = 256 + (tid >> 3);
        int pos = w0m + jl;
        if (pos >= 320) pos -= 320;
        __half* xd = &XS[pos * 136 + (tid & 7) * 16];
        sth8(xd, gX0);
        sth8(xd + 8, gX1);
      }
    }
    __syncthreads();  // (2) staged data visible

    // ---- ac = qu . K^T (B-frags shared across mt) ----
    f32x4 acc[2][4];
#pragma unroll
    for (int mt = 0; mt < 2; ++mt)
#pragma unroll
      for (int nt = 0; nt < 4; ++nt) acc[mt][nt] = (f32x4){0.f, 0.f, 0.f, 0.f};
#pragma unroll
    for (int ks = 0; ks < 4; ++ks) {
#pragma unroll
      for (int nt = 0; nt < 4; ++nt) {
        const half8 bfr = ldh8(&KS[(16 * nt + lrow) * 136 + lk8 + 32 * ks]);
        acc[0][nt] = mfma16(a[0][ks], bfr, acc[0][nt]);
        acc[1][nt] = mfma16(a[1][ks], bfr, acc[1][nt]);
      }
    }

    float lg[2][4][4];
    if (isC) {
#pragma unroll
      for (int nt = 0; nt < 4; ++nt) {
        const float bv = biasv[sBase + s0 + 16 * nt + lrow];
#pragma unroll
        for (int mt = 0; mt < 2; ++mt)
#pragma unroll
          for (int reg = 0; reg < 4; ++reg)
            lg[mt][nt][reg] = acc[mt][nt][reg] * INV_TAU + bv;
      }
    } else {
      // ---- bd: 6 shared X tiles feed both m-tiles' 5-tile windows ----
      const int base1 = 224 - cm0;
      int xrow[6];
      float dvv[6];
#pragma unroll
      for (int t = 0; t < 6; ++t) {
        int rr = w0m + base1 + 16 * t + lrow;
        if (rr >= 320) rr -= 320;
        xrow[t] = rr;
        int j = w0 + base1 + 16 * t + lrow;
        j = j > Wn - 1 ? Wn - 1 : j;
        dvv[t] = duv[h * Wn + j];
      }
      f32x4 eacc[2][5];
#pragma unroll
      for (int mt = 0; mt < 2; ++mt)
#pragma unroll
        for (int nt = 0; nt < 5; ++nt)
          eacc[mt][nt] = (f32x4){0.f, 0.f, 0.f, 0.f};
#pragma unroll
      for (int ks = 0; ks < 4; ++ks) {
        half8 xf[6];
#pragma unroll
        for (int t = 0; t < 6; ++t)
          xf[t] = ldh8(&XS[xrow[t] * 136 + lk8 + 32 * ks]);
#pragma unroll
        for (int nt = 0; nt < 5; ++nt) {
          eacc[1][nt] = mfma16(a[1][ks], xf[nt], eacc[1][nt]);
          eacc[0][nt] = mfma16(a[0][ks], xf[nt + 1], eacc[0][nt]);
        }
      }
#pragma unroll
      for (int mt = 0; mt < 2; ++mt) {
#pragma unroll
        for (int nt = 0; nt < 5; ++nt) {
          const float dv = (mt == 1) ? dvv[nt] : dvv[nt + 1];
#pragma unroll
          for (int reg = 0; reg < 4; ++reg)
            Sw[(4 * hi + reg) * 82 + 16 * nt + lrow] =
                __float2half(eacc[mt][nt][reg] + dv);
        }
#pragma unroll
        for (int nt = 0; nt < 4; ++nt) {
          const int kw = 16 * nt + lrow;
          const int w = w0 + kw;
#pragma unroll
          for (int reg = 0; reg < 4; ++reg) {
            const int cl = 4 * hi + reg;
            const int cabs = cm0 + 16 * mt + cl;
            const bool valid = (w <= cabs + Cn) && !(r == 0 && w < Cn);
            const float bdv = __half2float(Sw[cl * 82 + kw + 15 - cl]);
            lg[mt][nt][reg] =
                valid ? (acc[mt][nt][reg] + bdv) * INV_TAU : -NEGV;
          }
        }
      }
    }
    // ---- online softmax ----
    float p[2][4][4];
#pragma unroll
    for (int mt = 0; mt < 2; ++mt) {
#pragma unroll
      for (int reg = 0; reg < 4; ++reg) {
        float rm = fmaxf(fmaxf(lg[mt][0][reg], lg[mt][1][reg]),
                         fmaxf(lg[mt][2][reg], lg[mt][3][reg]));
        rm = fmaxf(rm, __shfl_xor(rm, 1));
        rm = fmaxf(rm, __shfl_xor(rm, 2));
        rm = fmaxf(rm, __shfl_xor(rm, 4));
        rm = fmaxf(rm, __shfl_xor(rm, 8));
        const float mn = fmaxf(mR[mt][reg], rm);
        const float scl = __expf(mR[mt][reg] - mn);
        float rs = 0.f;
#pragma unroll
        for (int nt = 0; nt < 4; ++nt) {
          p[mt][nt][reg] = __expf(lg[mt][nt][reg] - mn);
          rs += p[mt][nt][reg];
        }
        rs += __shfl_xor(rs, 1);
        rs += __shfl_xor(rs, 2);
        rs += __shfl_xor(rs, 4);
        rs += __shfl_xor(rs, 8);
        lR[mt][reg] = lR[mt][reg] * scl + rs;
        mR[mt][reg] = mn;
#pragma unroll
        for (int nt = 0; nt < 8; ++nt) Oacc[mt][nt][reg] *= scl;
      }
    }
    // ---- write P into wave-private SC [32][72] (no barrier needed) ----
#pragma unroll
    for (int mt = 0; mt < 2; ++mt)
#pragma unroll
      for (int nt = 0; nt < 4; ++nt)
#pragma unroll
        for (int reg = 0; reg < 4; ++reg)
          Sw[(16 * mt + 4 * hi + reg) * 72 + lrow + 16 * nt] =
              __float2half(p[mt][nt][reg]);
    // ---- PV (vv hoisted across mt) ----
#pragma unroll
    for (int ks = 0; ks < 2; ++ks) {
      const half8 pa0 = ldh8(&Sw[lrow * 72 + lk8 + 32 * ks]);
      const half8 pa1 = ldh8(&Sw[(16 + lrow) * 72 + lk8 + 32 * ks]);
#pragma unroll
      for (int nt = 0; nt < 8; ++nt) {
        const int gidx = (((lk8 + 32 * ks) >> 3) ^ nt);
        const half8 vv = ldh8(&VtS[(16 * nt + lrow) * 72 + gidx * 8]);
        Oacc[0][nt] = mfma16(pa0, vv, Oacc[0][nt]);
        Oacc[1][nt] = mfma16(pa1, vv, Oacc[1][nt]);
      }
    }
  }
  // ---- epilogue ----
#pragma unroll
  for (int mt = 0; mt < 2; ++mt) {
    float inv[4];
#pragma unroll
    for (int reg = 0; reg < 4; ++reg) inv[reg] = 1.0f / lR[mt][reg];
#pragma unroll
    for (int nt = 0; nt < 8; ++nt)
#pragma unroll
      for (int reg = 0; reg < 4; ++reg) {
        const int c = cm0 + 16 * mt + 4 * hi + reg;
        aout[((size_t)b * Tn + tBlk + c) * (Hn * Vn) + h * Vn + 16 * nt +
             lrow] = __float2half(Oacc[mt][nt][reg] * inv[reg]);
      }
  }
}

// ---------------- launcher ----------------
extern "C" void kernel_launch(void* const* d_in, const int* in_sizes, int n_in,
                              void* d_out, int out_size, void* d_ws,
                              size_t ws_size, hipStream_t stream) {
  (void)in_sizes;
  (void)n_in;
  (void)out_size;
  const float* x = (const float*)d_in[0];
  const float* g_ln = (const float*)d_in[1];
  const float* Wq = (const float*)d_in[2];
  const float* Wk = (const float*)d_in[3];
  const float* Wv = (const float*)d_in[4];
  const float* cb = (const float*)d_in[5];
  const float* xl_r = (const float*)d_in[6];
  const float* xl_u = (const float*)d_in[7];
  const float* xl_v = (const float*)d_in[8];
  const float* Wo = (const float*)d_in[9];
  float* out = (float*)d_out;

  float* W = (float*)d_ws;
  size_t o = 0;
  __half* xth = (__half*)(W + o);         // aliased later by aout (exact fit)
  __half* aout = xth;
  o += (size_t)Bn * Tn * Dn / 2;          // 4,194,304
  __half* xtl = (__half*)(W + o);
  o += (size_t)Bn * Tn * Dn / 2;          // 4,194,304
  __half* kbh = (__half*)(W + o);         // k hi/lo; aliased later by udl
  __half* udlh = kbh;                     // udl spans kbh+kbl (33.5 MB)
  o += (size_t)Hn * Bn * Tn * Kn / 2;     // 4,194,304
  __half* kbl = (__half*)(W + o);
  o += (size_t)Hn * Bn * Tn * Kn / 2;     // 4,194,304
  __half* qbh = (__half*)(W + o);
  o += (size_t)Hn * Bn * Tn * Kn / 2;     // 2,097,152
  __half* vbh = (__half*)(W + o);
  o += (size_t)Hn * Bn * Tn * Vn / 2;     // 2,097,152
  __half* cbh = (__half*)(W + o);
  o += (size_t)Hn * Sn * Kn / 2;          // 131,072
  __half* cbl = (__half*)(W + o);
  o += (size_t)Hn * Sn * Kn / 2;
  __half* xlrh = (__half*)(W + o);
  o += (size_t)Hn * Wn * Kn / 2;
  int* zb = (int*)(W + o);
  o += (size_t)Hn * Bn * Tn;              // 65,536
  float* biasb = W + o;
  o += (size_t)Hn * Bn * Rn * Sn;         // 131,072
  float* duvb = W + o;
  o += (size_t)Hn * Wn;                   // 4,096
  float* cb2b = W + o;
  o += (size_t)Hn * Sn;                   // 4,096
  __half* wkth = (__half*)(W + o);
  o += (size_t)Dn * Dn / 2;               // 524,288
  __half* wktl = (__half*)(W + o);
  o += (size_t)Dn * Dn / 2;
  __half* wqt = (__half*)(W + o);
  o += (size_t)Dn * Dn / 2;
  __half* wvt = (__half*)(W + o);
  o += (size_t)Dn * Dn / 2;
  __half* wot = (__half*)(W + o);
  o += (size_t)Dn * Dn / 2;

  if (ws_size < o * sizeof(float)) return;  // bail visibly if ws too small

  rms3_k<<<Bn * Tn, 256, 0, stream>>>(x, g_ln, xth, xtl);
  transall_k<<<dim3(32, 32, 4), 256, 0, stream>>>(Wq, Wv, Wo, Wk, wqt, wvt,
                                                  wot, wkth, wktl);
  cb2_k<<<Hn * Sn / 256, 256, 0, stream>>>(cb, cb2b);
  cvt2_k<<<2 * Hn * Sn * Kn / 256, 256, 0, stream>>>(cb, xl_r, cbh, cbl, xlrh);
  duv_k<<<Hn, 256, 0, stream>>>(xl_r, xl_u, xl_v, duvb);

  kproj_k<<<dim3(64, 8), 256, 0, stream>>>(xth, xtl, wkth, wktl, kbh, kbl,
                                           8192, 1024);
  gemmh_k<0><<<dim3(64, 8), 256, 0, stream>>>(xth, wqt, qbh, 8192, 1024, 1024);
  gemmh_k<0><<<dim3(64, 8), 256, 0, stream>>>(xth, wvt, vbh, 8192, 1024, 1024);

  argmin3_k<<<dim3(Bn * Tn / 128, Hn), 256, 0, stream>>>(kbh, kbl, cbh, cbl,
                                                         cb2b, zb);
  scan2_k<<<dim3(8, Bn, Hn), 1024, 0, stream>>>(zb, vbh, udlh, biasb);

  attn10_k<<<dim3(Bn * Rn, Hn), 512, 0, stream>>>(
      qbh, vbh, udlh, cbh, xlrh, biasb, duvb, zb, xl_u, aout);

  gemmh_k<1><<<dim3(64, 8), 256, 0, stream>>>(aout, wot, out, 8192, 1024,
                                              1024);
}

// Round 14
// 372.351 us; speedup vs baseline: 1.0690x; 1.0690x over previous
//
#include <hip/hip_runtime.h>
#include <hip/hip_fp16.h>

typedef _Float16 half8 __attribute__((ext_vector_type(8)));
typedef float f32x4 __attribute__((ext_vector_type(4)));

constexpr int Bn = 4, Tn = 2048, Dn = 1024, Hn = 8, Kn = 128, Vn = 128;
constexpr int Sn = 512, Cn = 256, Rn = 8, Wn = 512;
constexpr float NEGV = 1.0e30f;
constexpr float INV_TAU = 0.08838834764831845f;  // 1/sqrt(128)

__device__ __forceinline__ half8 ldh8(const __half* p) {
  return *reinterpret_cast<const half8*>(p);
}
__device__ __forceinline__ void sth8(__half* p, half8 v) {
  *reinterpret_cast<half8*>(p) = v;
}
__device__ __forceinline__ f32x4 mfma16(half8 a, half8 b, f32x4 c) {
  return __builtin_amdgcn_mfma_f32_16x16x32_f16(a, b, c, 0, 0, 0);
}

// ---------------- RMSNorm -> split f16 (hi + residual) ----------------
__global__ __launch_bounds__(256) void rms3_k(const float* __restrict__ x,
                                              const float* __restrict__ g,
                                              __half* __restrict__ xth,
                                              __half* __restrict__ xtl) {
  const int row = blockIdx.x;
  const int tid = threadIdx.x;
  const float4 v = reinterpret_cast<const float4*>(x + (size_t)row * Dn)[tid];
  float ss = v.x * v.x + v.y * v.y + v.z * v.z + v.w * v.w;
#pragma unroll
  for (int o = 32; o > 0; o >>= 1) ss += __shfl_xor(ss, o);
  __shared__ float red[4];
  if ((tid & 63) == 0) red[tid >> 6] = ss;
  __syncthreads();
  const float tot = red[0] + red[1] + red[2] + red[3];
  const float sc = rsqrtf(tot * (1.0f / Dn) + 1e-6f);
  const float4 gv = reinterpret_cast<const float4*>(g)[tid];
  float vv[4] = {v.x * sc * gv.x, v.y * sc * gv.y, v.z * sc * gv.z,
                 v.w * sc * gv.w};
  __half hi[4], lo[4];
#pragma unroll
  for (int e = 0; e < 4; ++e) {
    hi[e] = __float2half(vv[e]);
    lo[e] = __float2half(vv[e] - __half2float(hi[e]));
  }
  __half2* oph = reinterpret_cast<__half2*>(xth + (size_t)row * Dn + tid * 4);
  __half2* opl = reinterpret_cast<__half2*>(xtl + (size_t)row * Dn + tid * 4);
  oph[0] = __halves2half2(hi[0], hi[1]);
  oph[1] = __halves2half2(hi[2], hi[3]);
  opl[0] = __halves2half2(lo[0], lo[1]);
  opl[1] = __halves2half2(lo[2], lo[3]);
}

// -------- fused transpose+convert of all 4 weights (z selects) --------
__global__ __launch_bounds__(256) void transall_k(
    const float* __restrict__ Wq, const float* __restrict__ Wv,
    const float* __restrict__ Wo, const float* __restrict__ Wk,
    __half* __restrict__ wqt, __half* __restrict__ wvt,
    __half* __restrict__ wot, __half* __restrict__ wkth,
    __half* __restrict__ wktl) {
  __shared__ float ts[32][33];
  const int z = blockIdx.z;
  const float* src = (z == 0) ? Wq : (z == 1) ? Wv : (z == 2) ? Wo : Wk;
  const int bx = blockIdx.x, by = blockIdx.y;
  const int j = threadIdx.x & 31, i0 = threadIdx.x >> 5;
#pragma unroll
  for (int rr = 0; rr < 4; ++rr) {
    const int row = i0 + rr * 8;
    ts[row][j] = src[(size_t)(by * 32 + row) * 1024 + bx * 32 + j];
  }
  __syncthreads();
  if (z < 3) {
    __half* dst = (z == 0) ? wqt : (z == 1) ? wvt : wot;
#pragma unroll
    for (int rr = 0; rr < 4; ++rr) {
      const int row = i0 + rr * 8;
      dst[(size_t)(bx * 32 + row) * 1024 + by * 32 + j] =
          __float2half(ts[j][row]);
    }
  } else {
#pragma unroll
    for (int rr = 0; rr < 4; ++rr) {
      const int row = i0 + rr * 8;
      const float v = ts[j][row];
      const __half hi = __float2half(v);
      wkth[(size_t)(bx * 32 + row) * 1024 + by * 32 + j] = hi;
      wktl[(size_t)(bx * 32 + row) * 1024 + by * 32 + j] =
          __float2half(v - __half2float(hi));
    }
  }
}

// ---------------- codebook squared norms ----------------
__global__ __launch_bounds__(256) void cb2_k(const float* __restrict__ cb,
                                             float* __restrict__ cb2v) {
  const int idx = blockIdx.x * 256 + threadIdx.x;  // < H*S
  const float4* rp = reinterpret_cast<const float4*>(cb + (size_t)idx * Kn);
  float ss = 0.f;
#pragma unroll 8
  for (int i = 0; i < Kn / 4; ++i) {
    const float4 v = rp[i];
    ss += v.x * v.x + v.y * v.y + v.z * v.z + v.w * v.w;
  }
  cb2v[idx] = ss;
}

// -------- f32 -> f16 conversion: cb (hi+lo) and xl_r (hi only) --------
__global__ __launch_bounds__(256) void cvt2_k(const float* __restrict__ cb,
                                              const float* __restrict__ xlr,
                                              __half* __restrict__ cbh,
                                              __half* __restrict__ cbl,
                                              __half* __restrict__ xlrh) {
  const int i = blockIdx.x * 256 + threadIdx.x;
  constexpr int NE = Hn * Sn * Kn;  // 524288
  if (i < NE) {
    const float v = cb[i];
    const __half hi = __float2half(v);
    cbh[i] = hi;
    cbl[i] = __float2half(v - __half2float(hi));
  } else {
    xlrh[i - NE] = __float2half(xlr[i - NE]);
  }
}

// ---------------- duv[h][j] = (xl_v - xl_u) . xl_r[h][j] ----------------
__global__ __launch_bounds__(256) void duv_k(const float* __restrict__ xlr,
                                             const float* __restrict__ xlu,
                                             const float* __restrict__ xlv,
                                             float* __restrict__ duv) {
  const int h = blockIdx.x;
  const float* up = xlu + h * Kn;
  const float* vp = xlv + h * Kn;
  for (int j = threadIdx.x; j < Wn; j += 256) {
    const float* rp = xlr + ((size_t)h * Wn + j) * Kn;
    float s = 0.f;
#pragma unroll 8
    for (int d = 0; d < Kn; ++d) s = fmaf(vp[d] - up[d], rp[d], s);
    duv[h * Wn + j] = s;
  }
}

// ------- split-f16 MFMA k-projection: k = (xh+xl).(wh+wl), 3 terms ---------
__global__ __launch_bounds__(256, 2) void kproj_k(
    const __half* __restrict__ Ah, const __half* __restrict__ Al,
    const __half* __restrict__ Bh, const __half* __restrict__ Bl,
    __half* __restrict__ Ch, __half* __restrict__ Cl, int M, int KD) {
  __shared__ __half AsH[128 * 72];
  __shared__ __half AsL[128 * 72];
  __shared__ __half BsH[128 * 72];
  __shared__ __half BsL[128 * 72];
  const int tid = threadIdx.x;
  const int lane = tid & 63, wq = tid >> 6;
  const int lrow = lane & 15, lk8 = (lane >> 4) << 3;
  const int m0 = blockIdx.x * 128, n0 = blockIdx.y * 128;
  const int srow = tid >> 2, spart = tid & 3;

  f32x4 acc[2][8];
#pragma unroll
  for (int mt = 0; mt < 2; ++mt)
#pragma unroll
    for (int nt = 0; nt < 8; ++nt) acc[mt][nt] = (f32x4){0.f, 0.f, 0.f, 0.f};

  for (int kt = 0; kt < KD; kt += 64) {
    __syncthreads();
#pragma unroll
    for (int hh = 0; hh < 2; ++hh) {
      const int row = srow + hh * 64;
      const size_t ao = (size_t)(m0 + row) * KD + kt + spart * 16;
      const size_t bo = (size_t)(n0 + row) * KD + kt + spart * 16;
      sth8(&AsH[row * 72 + spart * 16], ldh8(Ah + ao));
      sth8(&AsH[row * 72 + spart * 16 + 8], ldh8(Ah + ao + 8));
      sth8(&AsL[row * 72 + spart * 16], ldh8(Al + ao));
      sth8(&AsL[row * 72 + spart * 16 + 8], ldh8(Al + ao + 8));
      sth8(&BsH[row * 72 + spart * 16], ldh8(Bh + bo));
      sth8(&BsH[row * 72 + spart * 16 + 8], ldh8(Bh + bo + 8));
      sth8(&BsL[row * 72 + spart * 16], ldh8(Bl + bo));
      sth8(&BsL[row * 72 + spart * 16 + 8], ldh8(Bl + bo + 8));
    }
    __syncthreads();
#pragma unroll
    for (int ks = 0; ks < 2; ++ks) {
      const half8 a0h = ldh8(&AsH[(32 * wq + lrow) * 72 + lk8 + 32 * ks]);
      const half8 a1h = ldh8(&AsH[(32 * wq + 16 + lrow) * 72 + lk8 + 32 * ks]);
      const half8 a0l = ldh8(&AsL[(32 * wq + lrow) * 72 + lk8 + 32 * ks]);
      const half8 a1l = ldh8(&AsL[(32 * wq + 16 + lrow) * 72 + lk8 + 32 * ks]);
#pragma unroll
      for (int nt = 0; nt < 8; ++nt) {
        const half8 bh = ldh8(&BsH[(16 * nt + lrow) * 72 + lk8 + 32 * ks]);
        const half8 bl = ldh8(&BsL[(16 * nt + lrow) * 72 + lk8 + 32 * ks]);
        acc[0][nt] = mfma16(a0h, bh, acc[0][nt]);
        acc[0][nt] = mfma16(a0h, bl, acc[0][nt]);
        acc[0][nt] = mfma16(a0l, bh, acc[0][nt]);
        acc[1][nt] = mfma16(a1h, bh, acc[1][nt]);
        acc[1][nt] = mfma16(a1h, bl, acc[1][nt]);
        acc[1][nt] = mfma16(a1l, bh, acc[1][nt]);
      }
    }
  }
  __half* OH = Ch + (size_t)(n0 >> 7) * M * 128;
  __half* OL = Cl + (size_t)(n0 >> 7) * M * 128;
#pragma unroll
  for (int mt = 0; mt < 2; ++mt)
#pragma unroll
    for (int nt = 0; nt < 8; ++nt)
#pragma unroll
      for (int reg = 0; reg < 4; ++reg) {
        const int row = m0 + 32 * wq + 16 * mt + 4 * (lane >> 4) + reg;
        const float v = acc[mt][nt][reg];
        const __half hi = __float2half(v);
        OH[(size_t)row * 128 + 16 * nt + lrow] = hi;
        OL[(size_t)row * 128 + 16 * nt + lrow] =
            __float2half(v - __half2float(hi));
      }
}

// ------------- f16 MFMA NT GEMM: C[m][n] = sum_k A[m][k] * Bt[n][k] --------
template <int MODE>
__global__ __launch_bounds__(256, 4) void gemmh_k(const __half* __restrict__ A,
                                                  const __half* __restrict__ Bt,
                                                  void* __restrict__ Cout,
                                                  int M, int N, int KD) {
  __shared__ __half As[128 * 72];
  __shared__ __half Bs[128 * 72];
  const int tid = threadIdx.x;
  const int lane = tid & 63, wq = tid >> 6;
  const int lrow = lane & 15, lk8 = (lane >> 4) << 3;
  const int m0 = blockIdx.x * 128, n0 = blockIdx.y * 128;
  const int srow = tid >> 2, spart = tid & 3;

  f32x4 acc[2][8];
#pragma unroll
  for (int mt = 0; mt < 2; ++mt)
#pragma unroll
    for (int nt = 0; nt < 8; ++nt) acc[mt][nt] = (f32x4){0.f, 0.f, 0.f, 0.f};

  for (int kt = 0; kt < KD; kt += 64) {
    __syncthreads();
#pragma unroll
    for (int hh = 0; hh < 2; ++hh) {
      const int row = srow + hh * 64;
      const __half* pa = A + (size_t)(m0 + row) * KD + kt + spart * 16;
      const __half* pb = Bt + (size_t)(n0 + row) * KD + kt + spart * 16;
      sth8(&As[row * 72 + spart * 16], ldh8(pa));
      sth8(&As[row * 72 + spart * 16 + 8], ldh8(pa + 8));
      sth8(&Bs[row * 72 + spart * 16], ldh8(pb));
      sth8(&Bs[row * 72 + spart * 16 + 8], ldh8(pb + 8));
    }
    __syncthreads();
#pragma unroll
    for (int ks = 0; ks < 2; ++ks) {
      half8 a0 = ldh8(&As[(32 * wq + lrow) * 72 + lk8 + 32 * ks]);
      half8 a1 = ldh8(&As[(32 * wq + 16 + lrow) * 72 + lk8 + 32 * ks]);
#pragma unroll
      for (int nt = 0; nt < 8; ++nt) {
        half8 b = ldh8(&Bs[(16 * nt + lrow) * 72 + lk8 + 32 * ks]);
        acc[0][nt] = mfma16(a0, b, acc[0][nt]);
        acc[1][nt] = mfma16(a1, b, acc[1][nt]);
      }
    }
  }
  if (MODE == 0) {
    __half* O = reinterpret_cast<__half*>(Cout) + (size_t)(n0 >> 7) * M * 128;
#pragma unroll
    for (int mt = 0; mt < 2; ++mt)
#pragma unroll
      for (int nt = 0; nt < 8; ++nt)
#pragma unroll
        for (int reg = 0; reg < 4; ++reg) {
          const int row = m0 + 32 * wq + 16 * mt + 4 * (lane >> 4) + reg;
          O[(size_t)row * 128 + 16 * nt + lrow] = __float2half(acc[mt][nt][reg]);
        }
  } else {
    float* O = reinterpret_cast<float*>(Cout);
#pragma unroll
    for (int mt = 0; mt < 2; ++mt)
#pragma unroll
      for (int nt = 0; nt < 8; ++nt)
#pragma unroll
        for (int reg = 0; reg < 4; ++reg) {
          const int row = m0 + 32 * wq + 16 * mt + 4 * (lane >> 4) + reg;
          O[(size_t)row * N + n0 + 16 * nt + lrow] = acc[mt][nt][reg];
        }
  }
}

// ---------- split-f16 MFMA dot + argmin: z = argmin_s ||k - c_s||^2 --------
__global__ __launch_bounds__(256, 2) void argmin3_k(
    const __half* __restrict__ kbh, const __half* __restrict__ kbl,
    const __half* __restrict__ cbh, const __half* __restrict__ cbl,
    const float* __restrict__ cb2v, int* __restrict__ zb) {
  __shared__ __half BsH[64 * 136];
  __shared__ __half BsL[64 * 136];
  const int tid = threadIdx.x;
  const int lane = tid & 63, wq = tid >> 6;
  const int lrow = lane & 15, lk8 = (lane >> 4) << 3;
  const int m0 = blockIdx.x * 128;
  const int h = blockIdx.y;
  const int srow = tid >> 2, spart = tid & 3;
  const size_t kbase = (size_t)h * (Bn * Tn);

  half8 ah[2][4], al[2][4];
#pragma unroll
  for (int mt = 0; mt < 2; ++mt)
#pragma unroll
    for (int ks = 0; ks < 4; ++ks) {
      const size_t off =
          (kbase + m0 + 32 * wq + 16 * mt + lrow) * 128 + lk8 + 32 * ks;
      ah[mt][ks] = ldh8(kbh + off);
      al[mt][ks] = ldh8(kbl + off);
    }

  float best[2][4];
  int bidx[2][4];
#pragma unroll
  for (int mt = 0; mt < 2; ++mt)
#pragma unroll
    for (int reg = 0; reg < 4; ++reg) {
      best[mt][reg] = 3.0e38f;
      bidx[mt][reg] = 0;
    }

  for (int s0 = 0; s0 < Sn; s0 += 64) {
    __syncthreads();
    {
      const size_t bo = ((size_t)h * Sn + s0 + srow) * 128 + spart * 32;
      sth8(&BsH[srow * 136 + spart * 32], ldh8(cbh + bo));
      sth8(&BsH[srow * 136 + spart * 32 + 8], ldh8(cbh + bo + 8));
      sth8(&BsH[srow * 136 + spart * 32 + 16], ldh8(cbh + bo + 16));
      sth8(&BsH[srow * 136 + spart * 32 + 24], ldh8(cbh + bo + 24));
      sth8(&BsL[srow * 136 + spart * 32], ldh8(cbl + bo));
      sth8(&BsL[srow * 136 + spart * 32 + 8], ldh8(cbl + bo + 8));
      sth8(&BsL[srow * 136 + spart * 32 + 16], ldh8(cbl + bo + 16));
      sth8(&BsL[srow * 136 + spart * 32 + 24], ldh8(cbl + bo + 24));
    }
    __syncthreads();
    f32x4 acc[2][4];
#pragma unroll
    for (int mt = 0; mt < 2; ++mt)
#pragma unroll
      for (int nt = 0; nt < 4; ++nt) acc[mt][nt] = (f32x4){0.f, 0.f, 0.f, 0.f};
#pragma unroll
    for (int ks = 0; ks < 4; ++ks)
#pragma unroll
      for (int nt = 0; nt < 4; ++nt) {
        const half8 bh = ldh8(&BsH[(16 * nt + lrow) * 136 + lk8 + 32 * ks]);
        const half8 bl = ldh8(&BsL[(16 * nt + lrow) * 136 + lk8 + 32 * ks]);
        acc[0][nt] = mfma16(ah[0][ks], bh, acc[0][nt]);
        acc[0][nt] = mfma16(ah[0][ks], bl, acc[0][nt]);
        acc[0][nt] = mfma16(al[0][ks], bh, acc[0][nt]);
        acc[1][nt] = mfma16(ah[1][ks], bh, acc[1][nt]);
        acc[1][nt] = mfma16(ah[1][ks], bl, acc[1][nt]);
        acc[1][nt] = mfma16(al[1][ks], bh, acc[1][nt]);
      }
#pragma unroll
    for (int mt = 0; mt < 2; ++mt)
#pragma unroll
      for (int nt = 0; nt < 4; ++nt) {
        const int s = s0 + 16 * nt + lrow;
        const float c2 = cb2v[h * Sn + s];
#pragma unroll
        for (int reg = 0; reg < 4; ++reg) {
          const float d2 = c2 - 2.0f * acc[mt][nt][reg];
          if (d2 < best[mt][reg]) {
            best[mt][reg] = d2;
            bidx[mt][reg] = s;
          }
        }
      }
  }
#pragma unroll
  for (int xb = 1; xb <= 8; xb <<= 1) {
#pragma unroll
    for (int mt = 0; mt < 2; ++mt)
#pragma unroll
      for (int reg = 0; reg < 4; ++reg) {
        const float ob = __shfl_xor(best[mt][reg], xb);
        const int oi = __shfl_xor(bidx[mt][reg], xb);
        if (ob < best[mt][reg] ||
            (ob == best[mt][reg] && oi < bidx[mt][reg])) {
          best[mt][reg] = ob;
          bidx[mt][reg] = oi;
        }
      }
  }
  if (lrow == 0) {
#pragma unroll
    for (int mt = 0; mt < 2; ++mt)
#pragma unroll
      for (int reg = 0; reg < 4; ++reg) {
        const int row = m0 + 32 * wq + 16 * mt + 4 * (lane >> 4) + reg;
        zb[kbase + row] = bidx[mt][reg];
      }
  }
}

// ------- scan2: cumulative cluster stats, 256 blocks x 1024 thr ------------
__global__ __launch_bounds__(1024) void scan2_k(const int* __restrict__ zb,
                                                const __half* __restrict__ vb,
                                                __half* __restrict__ udl,
                                                float* __restrict__ biasv) {
  __shared__ float acc[64][128];
  __shared__ float cnt[64];
  const int tid = threadIdx.x;
  const int sc = blockIdx.x, b = blockIdx.y, h = blockIdx.z;
  const int s0 = sc * 64;
  for (int i = tid; i < 64 * 128; i += 1024) acc[i >> 7][i & 127] = 0.f;
  if (tid < 64) cnt[tid] = 0.f;
  __syncthreads();
  const size_t tokH = (size_t)h * (Bn * Tn) + (size_t)b * Tn;
  const int dd = tid & 127, slice = tid >> 7;  // 8 slices
  for (int r = 0; r < Rn; ++r) {
    for (int i = tid; i < 64 * 128; i += 1024) {
      const int srow = i >> 7, d = i & 127;
      const float c = cnt[srow];
      udl[((((size_t)h * Bn + b) * Rn + r) * Sn + s0 + srow) * Vn + d] =
          __float2half(acc[srow][d] / fmaxf(c, 1.f));
    }
    if (tid < 64) {
      const float c = cnt[tid];
      biasv[(((size_t)h * Bn + b) * Rn + r) * Sn + s0 + tid] =
          (c > 0.f) ? logf(c) : -NEGV;
    }
    __syncthreads();
    if (r >= 1 && r < 7) {
      const int tb = (r - 1) * Cn;
#pragma unroll 4
      for (int u = 0; u < 32; ++u) {
        const int tok = tb + u * 8 + slice;
        const int s = zb[tokH + tok];
        if (s >= s0 && s < s0 + 64) {
          const float v = __half2float(vb[(tokH + tok) * Vn + dd]);
          atomicAdd(&acc[s - s0][dd], v);
          if (dd == 0) atomicAdd(&cnt[s - s0], 1.0f);
        }
      }
    }
    __syncthreads();
  }
}

// ------ MFMA fused attention v9 (best): circular xlr + vv-hoist + shared bd
// 1 block per (b,r,h), 512 thr = 8 waves; wave owns 32 rows (2 m-tiles).
__global__ __launch_bounds__(512, 2) void attn9_k(
    const __half* __restrict__ qbh, const __half* __restrict__ vbh,
    const __half* __restrict__ udl, const __half* __restrict__ cbh,
    const __half* __restrict__ xlrh, const float* __restrict__ biasv,
    const float* __restrict__ duv, const int* __restrict__ zb,
    const float* __restrict__ xlu, __half* __restrict__ aout) {
  __shared__ __half XS[320 * 136];   // circular xlr window (mod 320)
  __shared__ __half KS[64 * 136];    // K chunk
  __shared__ __half VtS[128 * 72];   // V^T chunk (XOR-swizzled granules)
  __shared__ __half SC[8 * 2304];    // per-wave scratch: E [16][82] / P [32][72]

  const int tid = threadIdx.x;
  const int lane = tid & 63, wq = tid >> 6;
  const int lrow = lane & 15, hi = lane >> 4, lk8 = hi << 3;
  const int bx = blockIdx.x;
  const int b = bx >> 3, r = bx & 7;
  const int h = blockIdx.y;
  const int cm0 = 32 * wq;
  const size_t tokH = (size_t)h * (Bn * Tn) + (size_t)b * Tn;
  const size_t sBase = (((size_t)h * Bn + b) * Rn + r) * Sn;
  const int tBlk = r * Cn;
  __half* Sw = &SC[wq * 2304];

  // A-frags: qu = q + xl_u (rows cm0+16mt+lrow)
  half8 a[2][4];
#pragma unroll
  for (int mt = 0; mt < 2; ++mt) {
    const size_t qrow = (tokH + tBlk + cm0 + 16 * mt + lrow) * Kn;
#pragma unroll
    for (int ks = 0; ks < 4; ++ks) {
      const int col = lk8 + 32 * ks;
      half8 q = ldh8(qbh + qrow + col);
      const float* up = xlu + h * Kn + col;
      half8 t;
#pragma unroll
      for (int e = 0; e < 8; ++e) t[e] = (_Float16)((float)q[e] + up[e]);
      a[mt][ks] = t;
    }
  }

  float mR[2][4], lR[2][4];
  f32x4 Oacc[2][8];
#pragma unroll
  for (int mt = 0; mt < 2; ++mt) {
#pragma unroll
    for (int i = 0; i < 4; ++i) {
      mR[mt][i] = -NEGV;
      lR[mt][i] = 0.f;
    }
#pragma unroll
    for (int nt = 0; nt < 8; ++nt) Oacc[mt][nt] = (f32x4){0.f, 0.f, 0.f, 0.f};
  }

  const int krow = tid >> 3, kpart = tid & 7;   // K staging
  const int kp = tid >> 4, p16 = tid & 15;      // Vt staging

  // r==0: cache + recent-prev masked -> chunks 12..15; r==1: cache masked
  const int chStart = (r >= 2) ? 0 : ((r == 1) ? 8 : 12);
  const int chFirstRecent = (chStart > 8) ? chStart : 8;

  for (int ch = chStart; ch < 16; ++ch) {
    const bool isC = (ch < 8);
    const int s0 = ch * 64;
    const int w0 = (ch - 8) * 64;
    const int w0m = (w0 >= 320) ? w0 - 320 : w0;  // w0 mod 320
    __syncthreads();  // (1) prior chunk LDS reads complete
    if (isC) {
      // K = codebook rows s0..s0+63
      {
        const __half* ks = cbh + ((size_t)h * Sn + s0 + krow) * Kn + kpart * 16;
        sth8(&KS[krow * 136 + kpart * 16], ldh8(ks));
        sth8(&KS[krow * 136 + kpart * 16 + 8], ldh8(ks + 8));
      }
      // Vt = udl rows
      {
        const __half* u0 = udl + (sBase + s0 + 2 * kp) * Vn + p16 * 8;
        const __half* u1 = u0 + Vn;
#pragma unroll
        for (int e = 0; e < 8; ++e) {
          const int d = p16 * 8 + e;
          const int gidx = ((2 * kp) >> 3) ^ ((d >> 4) & 7);
          *reinterpret_cast<__half2*>(
              &VtS[d * 72 + gidx * 8 + ((2 * kp) & 7)]) =
              __halves2half2(u0[e], u1[e]);
        }
      }
    } else {
      // K = gathered quantized keys
      {
        int tk = (r - 1) * Cn + w0 + krow;
        if (tk < 0) tk = 0;
        const int code = zb[tokH + tk];
        const __half* ks = cbh + ((size_t)h * Sn + code) * Kn + kpart * 16;
        sth8(&KS[krow * 136 + kpart * 16], ldh8(ks));
        sth8(&KS[krow * 136 + kpart * 16 + 8], ldh8(ks + 8));
      }
      // Vt = raw v rows
      {
        const int tk0 = (r - 1) * Cn + w0 + 2 * kp;
        const int tka = tk0 < 0 ? 0 : tk0;
        const int tkb = tk0 + 1 < 0 ? 0 : tk0 + 1;
        const __half* v0 = vbh + (tokH + tka) * Kn + p16 * 8;
        const __half* v1 = vbh + (tokH + tkb) * Kn + p16 * 8;
#pragma unroll
        for (int e = 0; e < 8; ++e) {
          const int d = p16 * 8 + e;
          const int gidx = ((2 * kp) >> 3) ^ ((d >> 4) & 7);
          *reinterpret_cast<__half2*>(
              &VtS[d * 72 + gidx * 8 + ((2 * kp) & 7)]) =
              __halves2half2(v0[e], v1[e]);
        }
      }
      // xlr circular staging: full window on first recent chunk, else 64 new
      if (ch == chFirstRecent) {
        for (int jl = tid >> 1; jl < 320; jl += 256) {
          const int p2 = tid & 1;
          int j = w0 + jl;
          j = j > Wn - 1 ? Wn - 1 : j;
          int pos = w0m + jl;
          if (pos >= 320) pos -= 320;
          const __half* xs = xlrh + ((size_t)h * Wn + j) * Kn + 64 * p2;
          __half* xd = &XS[pos * 136 + 64 * p2];
#pragma unroll
          for (int g8 = 0; g8 < 8; ++g8) sth8(xd + 8 * g8, ldh8(xs + 8 * g8));
        }
      } else {
        const int jl = 256 + (tid >> 3);
        int j = w0 + jl;
        j = j > Wn - 1 ? Wn - 1 : j;
        int pos = w0m + jl;
        if (pos >= 320) pos -= 320;
        const __half* xs = xlrh + ((size_t)h * Wn + j) * Kn + (tid & 7) * 16;
        __half* xd = &XS[pos * 136 + (tid & 7) * 16];
        sth8(xd, ldh8(xs));
        sth8(xd + 8, ldh8(xs + 8));
      }
    }
    __syncthreads();  // (2) staged data visible

    // ---- ac = qu . K^T (B-frags shared across mt) ----
    f32x4 acc[2][4];
#pragma unroll
    for (int mt = 0; mt < 2; ++mt)
#pragma unroll
      for (int nt = 0; nt < 4; ++nt) acc[mt][nt] = (f32x4){0.f, 0.f, 0.f, 0.f};
#pragma unroll
    for (int ks = 0; ks < 4; ++ks) {
#pragma unroll
      for (int nt = 0; nt < 4; ++nt) {
        const half8 bfr = ldh8(&KS[(16 * nt + lrow) * 136 + lk8 + 32 * ks]);
        acc[0][nt] = mfma16(a[0][ks], bfr, acc[0][nt]);
        acc[1][nt] = mfma16(a[1][ks], bfr, acc[1][nt]);
      }
    }

    float lg[2][4][4];
    if (isC) {
#pragma unroll
      for (int nt = 0; nt < 4; ++nt) {
        const float bv = biasv[sBase + s0 + 16 * nt + lrow];
#pragma unroll
        for (int mt = 0; mt < 2; ++mt)
#pragma unroll
          for (int reg = 0; reg < 4; ++reg)
            lg[mt][nt][reg] = acc[mt][nt][reg] * INV_TAU + bv;
      }
    } else {
      // ---- bd: 6 shared X tiles feed both m-tiles' 5-tile windows ----
      const int base1 = 224 - cm0;
      int xrow[6];
      float dvv[6];
#pragma unroll
      for (int t = 0; t < 6; ++t) {
        int rr = w0m + base1 + 16 * t + lrow;
        if (rr >= 320) rr -= 320;
        xrow[t] = rr;
        int j = w0 + base1 + 16 * t + lrow;
        j = j > Wn - 1 ? Wn - 1 : j;
        dvv[t] = duv[h * Wn + j];
      }
      f32x4 eacc[2][5];
#pragma unroll
      for (int mt = 0; mt < 2; ++mt)
#pragma unroll
        for (int nt = 0; nt < 5; ++nt)
          eacc[mt][nt] = (f32x4){0.f, 0.f, 0.f, 0.f};
#pragma unroll
      for (int ks = 0; ks < 4; ++ks) {
        half8 xf[6];
#pragma unroll
        for (int t = 0; t < 6; ++t)
          xf[t] = ldh8(&XS[xrow[t] * 136 + lk8 + 32 * ks]);
#pragma unroll
        for (int nt = 0; nt < 5; ++nt) {
          eacc[1][nt] = mfma16(a[1][ks], xf[nt], eacc[1][nt]);
          eacc[0][nt] = mfma16(a[0][ks], xf[nt + 1], eacc[0][nt]);
        }
      }
#pragma unroll
      for (int mt = 0; mt < 2; ++mt) {
#pragma unroll
        for (int nt = 0; nt < 5; ++nt) {
          const float dv = (mt == 1) ? dvv[nt] : dvv[nt + 1];
#pragma unroll
          for (int reg = 0; reg < 4; ++reg)
            Sw[(4 * hi + reg) * 82 + 16 * nt + lrow] =
                __float2half(eacc[mt][nt][reg] + dv);
        }
#pragma unroll
        for (int nt = 0; nt < 4; ++nt) {
          const int kw = 16 * nt + lrow;
          const int w = w0 + kw;
#pragma unroll
          for (int reg = 0; reg < 4; ++reg) {
            const int cl = 4 * hi + reg;
            const int cabs = cm0 + 16 * mt + cl;
            const bool valid = (w <= cabs + Cn) && !(r == 0 && w < Cn);
            const float bdv = __half2float(Sw[cl * 82 + kw + 15 - cl]);
            lg[mt][nt][reg] =
                valid ? (acc[mt][nt][reg] + bdv) * INV_TAU : -NEGV;
          }
        }
      }
    }
    // ---- online softmax ----
    float p[2][4][4];
#pragma unroll
    for (int mt = 0; mt < 2; ++mt) {
#pragma unroll
      for (int reg = 0; reg < 4; ++reg) {
        float rm = fmaxf(fmaxf(lg[mt][0][reg], lg[mt][1][reg]),
                         fmaxf(lg[mt][2][reg], lg[mt][3][reg]));
        rm = fmaxf(rm, __shfl_xor(rm, 1));
        rm = fmaxf(rm, __shfl_xor(rm, 2));
        rm = fmaxf(rm, __shfl_xor(rm, 4));
        rm = fmaxf(rm, __shfl_xor(rm, 8));
        const float mn = fmaxf(mR[mt][reg], rm);
        const float scl = __expf(mR[mt][reg] - mn);
        float rs = 0.f;
#pragma unroll
        for (int nt = 0; nt < 4; ++nt) {
          p[mt][nt][reg] = __expf(lg[mt][nt][reg] - mn);
          rs += p[mt][nt][reg];
        }
        rs += __shfl_xor(rs, 1);
        rs += __shfl_xor(rs, 2);
        rs += __shfl_xor(rs, 4);
        rs += __shfl_xor(rs, 8);
        lR[mt][reg] = lR[mt][reg] * scl + rs;
        mR[mt][reg] = mn;
#pragma unroll
        for (int nt = 0; nt < 8; ++nt) Oacc[mt][nt][reg] *= scl;
      }
    }
    // ---- write P into wave-private SC [32][72] (no barrier needed) ----
#pragma unroll
    for (int mt = 0; mt < 2; ++mt)
#pragma unroll
      for (int nt = 0; nt < 4; ++nt)
#pragma unroll
        for (int reg = 0; reg < 4; ++reg)
          Sw[(16 * mt + 4 * hi + reg) * 72 + lrow + 16 * nt] =
              __float2half(p[mt][nt][reg]);
    // ---- PV (vv hoisted across mt) ----
#pragma unroll
    for (int ks = 0; ks < 2; ++ks) {
      const half8 pa0 = ldh8(&Sw[lrow * 72 + lk8 + 32 * ks]);
      const half8 pa1 = ldh8(&Sw[(16 + lrow) * 72 + lk8 + 32 * ks]);
#pragma unroll
      for (int nt = 0; nt < 8; ++nt) {
        const int gidx = (((lk8 + 32 * ks) >> 3) ^ nt);
        const half8 vv = ldh8(&VtS[(16 * nt + lrow) * 72 + gidx * 8]);
        Oacc[0][nt] = mfma16(pa0, vv, Oacc[0][nt]);
        Oacc[1][nt] = mfma16(pa1, vv, Oacc[1][nt]);
      }
    }
  }
  // ---- epilogue ----
#pragma unroll
  for (int mt = 0; mt < 2; ++mt) {
    float inv[4];
#pragma unroll
    for (int reg = 0; reg < 4; ++reg) inv[reg] = 1.0f / lR[mt][reg];
#pragma unroll
    for (int nt = 0; nt < 8; ++nt)
#pragma unroll
      for (int reg = 0; reg < 4; ++reg) {
        const int c = cm0 + 16 * mt + 4 * hi + reg;
        aout[((size_t)b * Tn + tBlk + c) * (Hn * Vn) + h * Vn + 16 * nt +
             lrow] = __float2half(Oacc[mt][nt][reg] * inv[reg]);
      }
  }
}

// ---------------- launcher ----------------
extern "C" void kernel_launch(void* const* d_in, const int* in_sizes, int n_in,
                              void* d_out, int out_size, void* d_ws,
                              size_t ws_size, hipStream_t stream) {
  (void)in_sizes;
  (void)n_in;
  (void)out_size;
  const float* x = (const float*)d_in[0];
  const float* g_ln = (const float*)d_in[1];
  const float* Wq = (const float*)d_in[2];
  const float* Wk = (const float*)d_in[3];
  const float* Wv = (const float*)d_in[4];
  const float* cb = (const float*)d_in[5];
  const float* xl_r = (const float*)d_in[6];
  const float* xl_u = (const float*)d_in[7];
  const float* xl_v = (const float*)d_in[8];
  const float* Wo = (const float*)d_in[9];
  float* out = (float*)d_out;

  float* W = (float*)d_ws;
  size_t o = 0;
  __half* xth = (__half*)(W + o);         // aliased later by aout (exact fit)
  __half* aout = xth;
  o += (size_t)Bn * Tn * Dn / 2;
  __half* xtl = (__half*)(W + o);
  o += (size_t)Bn * Tn * Dn / 2;
  __half* kbh = (__half*)(W + o);         // k hi/lo; aliased later by udl
  __half* udlh = kbh;                     // udl spans kbh+kbl
  o += (size_t)Hn * Bn * Tn * Kn / 2;
  __half* kbl = (__half*)(W + o);
  o += (size_t)Hn * Bn * Tn * Kn / 2;
  __half* qbh = (__half*)(W + o);         // qbh then vbh contiguous
  o += (size_t)Hn * Bn * Tn * Kn / 2;
  __half* vbh = (__half*)(W + o);
  o += (size_t)Hn * Bn * Tn * Vn / 2;
  __half* cbh = (__half*)(W + o);
  o += (size_t)Hn * Sn * Kn / 2;
  __half* cbl = (__half*)(W + o);
  o += (size_t)Hn * Sn * Kn / 2;
  __half* xlrh = (__half*)(W + o);
  o += (size_t)Hn * Wn * Kn / 2;
  int* zb = (int*)(W + o);
  o += (size_t)Hn * Bn * Tn;
  float* biasb = W + o;
  o += (size_t)Hn * Bn * Rn * Sn;
  float* duvb = W + o;
  o += (size_t)Hn * Wn;
  float* cb2b = W + o;
  o += (size_t)Hn * Sn;
  __half* wkth = (__half*)(W + o);
  o += (size_t)Dn * Dn / 2;
  __half* wktl = (__half*)(W + o);
  o += (size_t)Dn * Dn / 2;
  __half* wqt = (__half*)(W + o);         // wqt then wvt contiguous
  o += (size_t)Dn * Dn / 2;
  __half* wvt = (__half*)(W + o);
  o += (size_t)Dn * Dn / 2;
  __half* wot = (__half*)(W + o);
  o += (size_t)Dn * Dn / 2;

  if (ws_size < o * sizeof(float)) return;  // bail visibly if ws too small

  rms3_k<<<Bn * Tn, 256, 0, stream>>>(x, g_ln, xth, xtl);
  transall_k<<<dim3(32, 32, 4), 256, 0, stream>>>(Wq, Wv, Wo, Wk, wqt, wvt,
                                                  wot, wkth, wktl);
  cb2_k<<<Hn * Sn / 256, 256, 0, stream>>>(cb, cb2b);
  cvt2_k<<<2 * Hn * Sn * Kn / 256, 256, 0, stream>>>(cb, xl_r, cbh, cbl, xlrh);
  duv_k<<<Hn, 256, 0, stream>>>(xl_r, xl_u, xl_v, duvb);

  kproj_k<<<dim3(64, 8), 256, 0, stream>>>(xth, xtl, wkth, wktl, kbh, kbl,
                                           8192, 1024);
  // fused q+v projections: B' = [wqt; wvt] (contiguous), heads 0-7 -> qbh,
  // heads 8-15 land exactly at vbh (contiguous after qbh)
  gemmh_k<0><<<dim3(64, 16), 256, 0, stream>>>(xth, wqt, qbh, 8192, 2048,
                                               1024);

  argmin3_k<<<dim3(Bn * Tn / 128, Hn), 256, 0, stream>>>(kbh, kbl, cbh, cbl,
                                                         cb2b, zb);
  scan2_k<<<dim3(8, Bn, Hn), 1024, 0, stream>>>(zb, vbh, udlh, biasb);

  attn9_k<<<dim3(Bn * Rn, Hn), 512, 0, stream>>>(
      qbh, vbh, udlh, cbh, xlrh, biasb, duvb, zb, xl_u, aout);

  gemmh_k<1><<<dim3(64, 8), 256, 0, stream>>>(aout, wot, out, 8192, 1024,
                                              1024);
}